// Round 2
// baseline (474.118 us; speedup 1.0000x reference)
//
#include <hip/hip_runtime.h>
#include <hip/hip_bf16.h>
#include <stdint.h>

// CommNetActor: B=8192, A=64 agents, OBS=128, D=64, NACT=32
//
// Math folding: comm layer  H' = Hcat @ W + b,  Hcat=[H_i, (S-H_i)/64]
//   = [H_i | S/64] @ [Wtop - Wbot/64 ; Wbot] + b     (K=128 MFMA, bias in acc init)
//
// v2: one wave = one sample. Weights as B-fragments in REGISTERS (loaded from
// L2-hot transposed copies), O loaded global->A-frag directly, H round-trips
// through a wave-PRIVATE LDS buffer (no __syncthreads anywhere).

#define BATCHN 8192

typedef __attribute__((ext_vector_type(8))) short short8;   // 8 bf16 (4 VGPRs)
typedef __attribute__((ext_vector_type(4))) float floatx4;  // MFMA acc

__device__ __forceinline__ unsigned short f2b(float f) {
    union { float f; uint32_t u; } v; v.f = f;
    uint32_t r = v.u + 0x7FFFu + ((v.u >> 16) & 1u);
    return (unsigned short)(r >> 16);
}

__device__ __forceinline__ uint32_t pk2(float x, float y) {
    float2 t; t.x = x; t.y = y;
    __hip_bfloat162 h = __float22bfloat162_rn(t);
    union { __hip_bfloat162 h; uint32_t u; } c; c.h = h;
    return c.u;
}

// ---- ws layout (byte offsets; ws treated as ushort*) ----
#define OFF_WENC 0                       // WencT  [64 n][128 k] bf16
#define OFF_WCAT 16384                   // WcatT  [4 l][64 n][128 k] bf16
#define OFF_WDEC 81920                   // WdecT  [32 n][4096 k] bf16
#define OFF_H4   344064                  // H4     [8192][4096] bf16

// ---------------- prep: transpose + bf16-convert weights ----------------
__global__ __launch_bounds__(256) void prep_kernel(
    const float* __restrict__ Wenc,
    const float* __restrict__ W1, const float* __restrict__ W2,
    const float* __restrict__ W3, const float* __restrict__ W4,
    const float* __restrict__ Wdec,
    unsigned short* __restrict__ ws)
{
    int tid = blockIdx.x * 256 + threadIdx.x;   // grid covers exactly 172032
    if (tid < 8192) {
        int n = tid >> 7, k = tid & 127;
        ws[OFF_WENC/2 + n*128 + k] = f2b(Wenc[k*64 + n]);
    } else if (tid < 5*8192) {
        int l = (tid - 8192) >> 13;
        int e = (tid - 8192) & 8191;
        int n = e >> 7, k = e & 127;
        const float* W = (l==0) ? W1 : (l==1) ? W2 : (l==2) ? W3 : W4;
        float v = W[k*64 + n];                       // k<64: Wtop, k>=64: Wbot
        if (k < 64) v -= W[(k+64)*64 + n] * (1.0f/64.0f);
        ws[OFF_WCAT/2 + l*8192 + n*128 + k] = f2b(v);
    } else {
        int e = tid - 5*8192;                        // 0..131071
        int n = e >> 12, k = e & 4095;
        ws[OFF_WDEC/2 + n*4096 + k] = f2b(Wdec[k*32 + n]);
    }
}

// ---------------- fused encoder + 4 comm layers (wave-per-sample) ----------------
__global__ __launch_bounds__(256, 2) void fused2_kernel(
    const float* __restrict__ O,
    const unsigned short* __restrict__ WencT,
    const unsigned short* __restrict__ WcatT,
    const float* __restrict__ b_enc,
    const float* __restrict__ b1, const float* __restrict__ b2,
    const float* __restrict__ b3, const float* __restrict__ b4,
    unsigned short* __restrict__ H4out)
{
    __shared__ unsigned short sH[4][64*72];   // per-wave private H buffer (pad 8)
    __shared__ unsigned short sS[4][72];      // per-wave private S/64 row

    const int t = threadIdx.x, lane = t & 63, w = t >> 6;
    const int m = lane & 15, q = lane >> 4;
    const int b = blockIdx.x * 4 + w;
    unsigned short* myH = sH[w];
    unsigned short* myS = sS[w];

    // per-lane biases (col = nt*16 + m), held for the whole kernel
    float bias[5][4];
    {
        const float* bp[5] = {b_enc, b1, b2, b3, b4};
        #pragma unroll
        for (int l = 0; l < 5; l++)
            #pragma unroll
            for (int nt = 0; nt < 4; nt++)
                bias[l][nt] = bp[l][nt*16 + m];
    }

    floatx4 acc[4][4];   // [mt][nt] 16 tiles = full 64x64
    short8  Bf[16];      // current layer B-frags [nt][s]

    // ---- encoder: H0 = sigmoid(O @ Wenc + b_enc), K=128 ----
    #pragma unroll
    for (int nt = 0; nt < 4; nt++)
        #pragma unroll
        for (int s = 0; s < 4; s++)
            Bf[nt*4+s] = *(const short8*)(WencT + (nt*16+m)*128 + s*32 + q*8);

    #pragma unroll
    for (int mt = 0; mt < 4; mt++)
        #pragma unroll
        for (int nt = 0; nt < 4; nt++)
            acc[mt][nt] = (floatx4){bias[0][nt], bias[0][nt], bias[0][nt], bias[0][nt]};

    const float* Ob = O + (size_t)b * 8192;
    #pragma unroll
    for (int s = 0; s < 4; s++) {
        short8 A[4];
        #pragma unroll
        for (int mt = 0; mt < 4; mt++) {
            const float* pr = Ob + (mt*16+m)*128 + s*32 + q*8;
            float4 f0 = *(const float4*)pr;
            float4 f1 = *(const float4*)(pr + 4);
            uint32_t* pa = (uint32_t*)&A[mt];
            pa[0] = pk2(f0.x, f0.y); pa[1] = pk2(f0.z, f0.w);
            pa[2] = pk2(f1.x, f1.y); pa[3] = pk2(f1.z, f1.w);
        }
        #pragma unroll
        for (int mt = 0; mt < 4; mt++)
            #pragma unroll
            for (int nt = 0; nt < 4; nt++)
                acc[mt][nt] = __builtin_amdgcn_mfma_f32_16x16x32_bf16(A[mt], Bf[nt*4+s], acc[mt][nt], 0, 0, 0);
    }
    #pragma unroll
    for (int mt = 0; mt < 4; mt++)
        #pragma unroll
        for (int nt = 0; nt < 4; nt++)
            #pragma unroll
            for (int r = 0; r < 4; r++)
                acc[mt][nt][r] = 1.0f / (1.0f + __expf(-acc[mt][nt][r]));

    // ---- 4 comm layers ----
    #pragma unroll
    for (int l = 1; l <= 4; l++) {
        // epilogue of previous layer: S (shuffle colsum) + H -> wave-private LDS
        #pragma unroll
        for (int nt = 0; nt < 4; nt++) {
            float s = 0.f;
            #pragma unroll
            for (int mt = 0; mt < 4; mt++)
                #pragma unroll
                for (int r = 0; r < 4; r++) s += acc[mt][nt][r];
            s += __shfl_xor(s, 16, 64);
            s += __shfl_xor(s, 32, 64);
            if (q == 0) myS[nt*16 + m] = f2b(s * (1.0f/64.0f));
        }
        #pragma unroll
        for (int mt = 0; mt < 4; mt++)
            #pragma unroll
            for (int nt = 0; nt < 4; nt++) {
                uint32_t p01 = pk2(acc[mt][nt][0], acc[mt][nt][1]);
                uint32_t p23 = pk2(acc[mt][nt][2], acc[mt][nt][3]);
                unsigned short* base = myH + (mt*16 + q*4)*72 + nt*16 + m;
                base[0]   = (unsigned short)p01;
                base[72]  = (unsigned short)(p01 >> 16);
                base[144] = (unsigned short)p23;
                base[216] = (unsigned short)(p23 >> 16);
            }

        // layer weights -> registers
        #pragma unroll
        for (int nt = 0; nt < 4; nt++)
            #pragma unroll
            for (int s = 0; s < 4; s++)
                Bf[nt*4+s] = *(const short8*)(WcatT + (l-1)*8192 + (nt*16+m)*128 + s*32 + q*8);

        #pragma unroll
        for (int mt = 0; mt < 4; mt++)
            #pragma unroll
            for (int nt = 0; nt < 4; nt++)
                acc[mt][nt] = (floatx4){bias[l][nt], bias[l][nt], bias[l][nt], bias[l][nt]};

        // k = 0..63 from H rows
        #pragma unroll
        for (int s2 = 0; s2 < 2; s2++) {
            short8 A[4];
            #pragma unroll
            for (int mt = 0; mt < 4; mt++)
                A[mt] = *(const short8*)(myH + (mt*16+m)*72 + s2*32 + q*8);
            #pragma unroll
            for (int mt = 0; mt < 4; mt++)
                #pragma unroll
                for (int nt = 0; nt < 4; nt++)
                    acc[mt][nt] = __builtin_amdgcn_mfma_f32_16x16x32_bf16(A[mt], Bf[nt*4+s2], acc[mt][nt], 0, 0, 0);
        }
        // k = 64..127: all A rows equal S/64 (LDS broadcast read)
        #pragma unroll
        for (int s2 = 0; s2 < 2; s2++) {
            short8 As = *(const short8*)(myS + s2*32 + q*8);
            #pragma unroll
            for (int mt = 0; mt < 4; mt++)
                #pragma unroll
                for (int nt = 0; nt < 4; nt++)
                    acc[mt][nt] = __builtin_amdgcn_mfma_f32_16x16x32_bf16(As, Bf[nt*4+2+s2], acc[mt][nt], 0, 0, 0);
        }
    }

    // ---- final store: H4 bf16 [sample][agent*64 + feat] ----
    unsigned short* Hb = H4out + (size_t)b * 4096;
    #pragma unroll
    for (int mt = 0; mt < 4; mt++)
        #pragma unroll
        for (int nt = 0; nt < 4; nt++) {
            uint32_t p01 = pk2(acc[mt][nt][0], acc[mt][nt][1]);
            uint32_t p23 = pk2(acc[mt][nt][2], acc[mt][nt][3]);
            unsigned short* base = Hb + (mt*16 + q*4)*64 + nt*16 + m;
            base[0]   = (unsigned short)p01;
            base[64]  = (unsigned short)(p01 >> 16);
            base[128] = (unsigned short)p23;
            base[192] = (unsigned short)(p23 >> 16);
        }
}

// ---------------- decoder: out = Hf @ Wdec + b_dec ----------------
// M=8192, N=32, K=4096; K-split x8, fp32 atomicAdd epilogue (out pre-zeroed).
__global__ __launch_bounds__(256) void dec_kernel(
    const unsigned short* __restrict__ Hf,     // [8192][4096] bf16
    const unsigned short* __restrict__ WdecT,  // [32][4096] bf16
    const float* __restrict__ b_dec,
    float* __restrict__ out)                   // [8192][32] fp32
{
    int gt = blockIdx.x * 256 + threadIdx.x;
    int wave = gt >> 6;          // 0..4095
    int lane = gt & 63;
    int rb = wave >> 3;          // rows [rb*16, rb*16+16)
    int kc = wave & 7;           // K chunk [kc*512, +512)
    int m = lane & 15, q = lane >> 4;

    const unsigned short* aP  = Hf    + (size_t)(rb*16 + m)*4096 + kc*512 + q*8;
    const unsigned short* bP0 = WdecT + (size_t)m*4096        + kc*512 + q*8;
    const unsigned short* bP1 = WdecT + (size_t)(16 + m)*4096 + kc*512 + q*8;

    floatx4 a0 = {0.f, 0.f, 0.f, 0.f}, a1 = {0.f, 0.f, 0.f, 0.f};
    #pragma unroll 4
    for (int s = 0; s < 16; s++) {
        short8 av  = *(const short8*)(aP  + s*32);
        short8 b0v = *(const short8*)(bP0 + s*32);
        short8 b1v = *(const short8*)(bP1 + s*32);
        a0 = __builtin_amdgcn_mfma_f32_16x16x32_bf16(av, b0v, a0, 0, 0, 0);
        a1 = __builtin_amdgcn_mfma_f32_16x16x32_bf16(av, b1v, a1, 0, 0, 0);
    }
    float bias0 = (kc == 0) ? b_dec[m]      : 0.0f;
    float bias1 = (kc == 0) ? b_dec[16 + m] : 0.0f;
    #pragma unroll
    for (int r = 0; r < 4; r++) {
        int row = rb*16 + q*4 + r;
        atomicAdd(&out[row*32 + m],      a0[r] + bias0);
        atomicAdd(&out[row*32 + 16 + m], a1[r] + bias1);
    }
}

extern "C" void kernel_launch(void* const* d_in, const int* in_sizes, int n_in,
                              void* d_out, int out_size, void* d_ws, size_t ws_size,
                              hipStream_t stream)
{
    const float* O    = (const float*)d_in[0];
    const float* Wenc = (const float*)d_in[1];
    const float* benc = (const float*)d_in[2];
    const float* W1   = (const float*)d_in[3];
    const float* b1   = (const float*)d_in[4];
    const float* W2   = (const float*)d_in[5];
    const float* b2   = (const float*)d_in[6];
    const float* W3   = (const float*)d_in[7];
    const float* b3   = (const float*)d_in[8];
    const float* W4   = (const float*)d_in[9];
    const float* b4   = (const float*)d_in[10];
    const float* Wdec = (const float*)d_in[11];
    const float* bdec = (const float*)d_in[12];
    float* out = (float*)d_out;
    unsigned short* ws = (unsigned short*)d_ws;

    hipMemsetAsync(d_out, 0, (size_t)out_size * sizeof(float), stream);
    prep_kernel<<<672, 256, 0, stream>>>(Wenc, W1, W2, W3, W4, Wdec, ws);
    fused2_kernel<<<2048, 256, 0, stream>>>(O, ws + OFF_WENC/2, ws + OFF_WCAT/2,
                                            benc, b1, b2, b3, b4, ws + OFF_H4/2);
    dec_kernel<<<1024, 256, 0, stream>>>(ws + OFF_H4/2, ws + OFF_WDEC/2, bdec, out);
}